// Round 10
// baseline (285.604 us; speedup 1.0000x reference)
//
#include <hip/hip_runtime.h>

#define IN_C 256
#define HIDC 32
#define OUTC 16
#define NPB  128          // nodes per bucket (d_local = 7 bits)
#define MAXBKT 800        // >= ceil(100000/128) = 782

// ---------------- edge index loader (handles int32 or int64 storage) -------
__device__ __forceinline__ int edge_at(const int* __restrict__ ei, long long idx, int is64) {
    return is64 ? ei[idx << 1] : ei[idx];
}

// Detect int64 vs int32 storage: sample odd 32-bit words; all-zero => int64.
__global__ void k_detect(const int* __restrict__ ei, int* __restrict__ flag) {
    __shared__ int nz;
    if (threadIdx.x == 0) nz = 0;
    __syncthreads();
    if (ei[2 * threadIdx.x + 1] != 0) atomicOr(&nz, 1);
    __syncthreads();
    if (threadIdx.x == 0) *flag = (nz == 0) ? 1 : 0;
}

// ---------------- bucket binning -------------------------------------------
// grid 1024 (round-9 lesson: 256 blocks = 1 block/CU = 12.5% occupancy cap,
// latency-naked; 1024 -> 4 blocks/CU, stalls hidden by TLP)
__global__ __launch_bounds__(256) void k_bin_count(const int* __restrict__ ei, long long E,
                                                   const int* __restrict__ flag,
                                                   int* __restrict__ bkt_cnt, int nbkt) {
    __shared__ int hist[MAXBKT];
    int is64 = *flag;
    for (int i = threadIdx.x; i < nbkt; i += 256) hist[i] = 0;
    __syncthreads();
    long long chunk = (E + gridDim.x - 1) / gridDim.x;
    long long lo = (long long)blockIdx.x * chunk;
    long long hi = lo + chunk; if (hi > E) hi = E;
    for (long long i = lo + threadIdx.x; i < hi; i += 256)
        atomicAdd(&hist[edge_at(ei, E + i, is64) >> 7], 1);
    __syncthreads();
    for (int b = threadIdx.x; b < nbkt; b += 256)
        if (hist[b]) atomicAdd(&bkt_cnt[b], hist[b]);
}

__global__ __launch_bounds__(512) void k_bscan(const int* __restrict__ bkt_cnt,
                                               int* __restrict__ bkt_base,
                                               int* __restrict__ bkt_cur, int nbkt) {
    __shared__ int sm[512];
    int t = threadIdx.x;
    int e0 = (2 * t < nbkt) ? bkt_cnt[2 * t] : 0;
    int e1 = (2 * t + 1 < nbkt) ? bkt_cnt[2 * t + 1] : 0;
    int pv = e0 + e1;
    sm[t] = pv;
    __syncthreads();
    for (int o = 1; o < 512; o <<= 1) {
        int x = (t >= o) ? sm[t - o] : 0;
        __syncthreads();
        sm[t] += x;
        __syncthreads();
    }
    int base = sm[t] - pv;  // exclusive over pairs
    if (2 * t < nbkt)     { bkt_base[2 * t] = base;          bkt_cur[2 * t] = base; }
    if (2 * t + 1 < nbkt) { bkt_base[2 * t + 1] = base + e0; bkt_cur[2 * t + 1] = base + e0; }
}

__global__ __launch_bounds__(256) void k_bin_scatter(const int* __restrict__ ei, long long E,
                                                     const int* __restrict__ flag,
                                                     int* __restrict__ bkt_cur,
                                                     unsigned* __restrict__ packed, int nbkt) {
    __shared__ int hist[MAXBKT];
    int is64 = *flag;
    for (int i = threadIdx.x; i < nbkt; i += 256) hist[i] = 0;
    __syncthreads();
    long long chunk = (E + gridDim.x - 1) / gridDim.x;
    long long lo = (long long)blockIdx.x * chunk;
    long long hi = lo + chunk; if (hi > E) hi = E;
    for (long long i = lo + threadIdx.x; i < hi; i += 256)
        atomicAdd(&hist[edge_at(ei, E + i, is64) >> 7], 1);
    __syncthreads();
    for (int b = threadIdx.x; b < nbkt; b += 256) {
        int c = hist[b];
        hist[b] = c ? atomicAdd(&bkt_cur[b], c) : 0;   // hist now = running cursor
    }
    __syncthreads();
    for (long long i = lo + threadIdx.x; i < hi; i += 256) {
        int s = edge_at(ei, i, is64);
        int d = edge_at(ei, E + i, is64);
        int slot = atomicAdd(&hist[d >> 7], 1);
        packed[slot] = (unsigned)s | ((unsigned)(d & (NPB - 1)) << 20);
    }
}

// ---------------- per-bucket counting sort -> node-level CSR ---------------
__global__ __launch_bounds__(256) void k_bucket_csr(const unsigned* __restrict__ packed,
                                                    const int* __restrict__ bkt_base,
                                                    const int* __restrict__ bkt_cnt,
                                                    int* __restrict__ csr_src,
                                                    int* __restrict__ ptr,
                                                    int* __restrict__ cnt,
                                                    float* __restrict__ dinv, int n) {
    __shared__ int hist[NPB];
    __shared__ int off[NPB];
    if (threadIdx.x < NPB) hist[threadIdx.x] = 0;
    __syncthreads();
    int base = bkt_base[blockIdx.x], m = bkt_cnt[blockIdx.x];
    for (int i = threadIdx.x; i < m; i += 256)
        atomicAdd(&hist[packed[base + i] >> 20], 1);
    __syncthreads();
    if (threadIdx.x < NPB) off[threadIdx.x] = hist[threadIdx.x];
    __syncthreads();
    for (int o = 1; o < NPB; o <<= 1) {
        int v = 0;
        if (threadIdx.x < NPB && threadIdx.x >= o) v = off[threadIdx.x - o];
        __syncthreads();
        if (threadIdx.x < NPB) off[threadIdx.x] += v;
        __syncthreads();
    }
    int node = blockIdx.x * NPB + threadIdx.x;
    if (threadIdx.x < NPB) {
        int exc = off[threadIdx.x] - hist[threadIdx.x];
        if (node < n) {
            ptr[node]  = base + exc;
            cnt[node]  = hist[threadIdx.x];
            dinv[node] = rsqrtf((float)hist[threadIdx.x] + 1.0f);
        }
        hist[threadIdx.x] = exc;                  // reuse as cursor
    }
    __syncthreads();
    for (int i = threadIdx.x; i < m; i += 256) {
        unsigned w = packed[base + i];
        int r = atomicAdd(&hist[w >> 20], 1);
        csr_src[base + r] = (int)(w & 0xFFFFF);   // write inside bucket window
    }
}

// ---------------- gemm1: h1s = (x @ W1) * dinv  [n,256]x[256,32] ------------
// lane = node (64/block); wave q fully owns o-octet [8q,8q+8) -> acc is 8
// STATIC scalars (round-8 lesson: runtime-indexed acc -> scratch). x and W
// both staged in LDS; W read as wave-uniform float4 broadcasts.
#define G1_NODES 64
__global__ __launch_bounds__(256) void k_gemm1(const float* __restrict__ x,
                                               const float* __restrict__ W1,
                                               const float* __restrict__ dinv,
                                               float* __restrict__ h1s, int n) {
    __shared__ float xs[G1_NODES][33];   // 8.4 KB; bank(lane,k) = (lane+k)%32
    __shared__ float wl[32][36];         // 4.6 KB; rows 16B-aligned (36%4==0)
    const int t = threadIdx.x;
    const int lane = t & 63;
    const int oq0 = (t >> 6) * 8;        // wave's o-octet base
    const long long nb0 = (long long)blockIdx.x * G1_NODES;
    const long long node = nb0 + lane;
    const bool valid = node < n;

    float a0 = 0.f, a1 = 0.f, a2 = 0.f, a3 = 0.f;
    float a4 = 0.f, a5 = 0.f, a6 = 0.f, a7 = 0.f;

    for (int c = 0; c < IN_C / 32; ++c) {          // 8 chunks of 32 k
        const int k0 = c * 32;
#pragma unroll
        for (int j = 0; j < 2; ++j) {
            int f = j * 256 + t;
            int row = f >> 3, c4 = f & 7;
            long long nd = nb0 + row;
            float4 v = make_float4(0.f, 0.f, 0.f, 0.f);
            if (nd < n) v = *(const float4*)(x + nd * IN_C + k0 + c4 * 4);
            xs[row][c4 * 4 + 0] = v.x; xs[row][c4 * 4 + 1] = v.y;
            xs[row][c4 * 4 + 2] = v.z; xs[row][c4 * 4 + 3] = v.w;
        }
        {
            int kk = t >> 3, o4 = (t & 7) * 4;
            float4 w = *(const float4*)(W1 + (long long)(k0 + kk) * HIDC + o4);
            wl[kk][o4 + 0] = w.x; wl[kk][o4 + 1] = w.y;
            wl[kk][o4 + 2] = w.z; wl[kk][o4 + 3] = w.w;
        }
        __syncthreads();
#pragma unroll
        for (int g = 0; g < 8; ++g) {              // 4 k per group
            const int kb = g * 4;
            float x0 = xs[lane][kb + 0];
            float x1 = xs[lane][kb + 1];
            float x2 = xs[lane][kb + 2];
            float x3 = xs[lane][kb + 3];
            float4 wa0 = *(const float4*)&wl[kb + 0][oq0];
            float4 wb0 = *(const float4*)&wl[kb + 0][oq0 + 4];
            float4 wa1 = *(const float4*)&wl[kb + 1][oq0];
            float4 wb1 = *(const float4*)&wl[kb + 1][oq0 + 4];
            float4 wa2 = *(const float4*)&wl[kb + 2][oq0];
            float4 wb2 = *(const float4*)&wl[kb + 2][oq0 + 4];
            float4 wa3 = *(const float4*)&wl[kb + 3][oq0];
            float4 wb3 = *(const float4*)&wl[kb + 3][oq0 + 4];
            a0 = fmaf(x0, wa0.x, a0); a1 = fmaf(x0, wa0.y, a1);
            a2 = fmaf(x0, wa0.z, a2); a3 = fmaf(x0, wa0.w, a3);
            a4 = fmaf(x0, wb0.x, a4); a5 = fmaf(x0, wb0.y, a5);
            a6 = fmaf(x0, wb0.z, a6); a7 = fmaf(x0, wb0.w, a7);
            a0 = fmaf(x1, wa1.x, a0); a1 = fmaf(x1, wa1.y, a1);
            a2 = fmaf(x1, wa1.z, a2); a3 = fmaf(x1, wa1.w, a3);
            a4 = fmaf(x1, wb1.x, a4); a5 = fmaf(x1, wb1.y, a5);
            a6 = fmaf(x1, wb1.z, a6); a7 = fmaf(x1, wb1.w, a7);
            a0 = fmaf(x2, wa2.x, a0); a1 = fmaf(x2, wa2.y, a1);
            a2 = fmaf(x2, wa2.z, a2); a3 = fmaf(x2, wa2.w, a3);
            a4 = fmaf(x2, wb2.x, a4); a5 = fmaf(x2, wb2.y, a5);
            a6 = fmaf(x2, wb2.z, a6); a7 = fmaf(x2, wb2.w, a7);
            a0 = fmaf(x3, wa3.x, a0); a1 = fmaf(x3, wa3.y, a1);
            a2 = fmaf(x3, wa3.z, a2); a3 = fmaf(x3, wa3.w, a3);
            a4 = fmaf(x3, wb3.x, a4); a5 = fmaf(x3, wb3.y, a5);
            a6 = fmaf(x3, wb3.z, a6); a7 = fmaf(x3, wb3.w, a7);
        }
        __syncthreads();
    }
    if (valid) {
        float di = dinv[node];
        *(float4*)(h1s + node * HIDC + oq0) =
            make_float4(a0 * di, a1 * di, a2 * di, a3 * di);
        *(float4*)(h1s + node * HIDC + oq0 + 4) =
            make_float4(a4 * di, a5 * di, a6 * di, a7 * di);
    }
}

// ---------------- layer-1 pull aggregation + fused finalize ----------------
__global__ __launch_bounds__(256) void k_agg1csr(const int* __restrict__ ptr,
                                                 const int* __restrict__ cnt,
                                                 const int* __restrict__ csr_src,
                                                 const float* __restrict__ dinv,
                                                 const float* __restrict__ h1s,
                                                 const float* __restrict__ b1,
                                                 float* __restrict__ h1r, int n) {
    long long g = (long long)blockIdx.x * blockDim.x + threadIdx.x;
    int node = (int)(g >> 5);
    int ch = (int)(g & 31);
    if (node >= n) return;
    float acc = h1s[(long long)node * HIDC + ch];   // self-loop term (x dinv already)
    int st = ptr[node], deg = cnt[node];
    int j = 0;
    for (; j + 3 < deg; j += 4) {
        int s0 = csr_src[st + j], s1 = csr_src[st + j + 1];
        int s2 = csr_src[st + j + 2], s3 = csr_src[st + j + 3];
        float a0 = h1s[(long long)s0 * HIDC + ch];
        float a1 = h1s[(long long)s1 * HIDC + ch];
        float a2 = h1s[(long long)s2 * HIDC + ch];
        float a3 = h1s[(long long)s3 * HIDC + ch];
        acc += (a0 + a1) + (a2 + a3);
    }
    for (; j < deg; ++j)
        acc += h1s[(long long)csr_src[st + j] * HIDC + ch];
    float v = acc * dinv[node] + b1[ch];
    h1r[(long long)node * HIDC + ch] = v > 0.f ? v : 0.f;
}

// ---------------- gemm2: h2s = (h1r @ W2) * dinv  [n,32]x[32,16] ------------
__global__ __launch_bounds__(256) void k_gemm2(const float* __restrict__ h1,
                                               const float* __restrict__ W2,
                                               const float* __restrict__ dinv,
                                               float* __restrict__ h2s, int n) {
    const int t = threadIdx.x;
    const int oq = (t & 3) * 4;
    const long long node = (long long)blockIdx.x * 64 + (t >> 2);
    if (node >= n) return;
    const float* __restrict__ xp = h1 + node * HIDC;
    float a0 = 0.f, a1 = 0.f, a2 = 0.f, a3 = 0.f;
#pragma unroll
    for (int k0 = 0; k0 < HIDC; k0 += 8) {
        float4 xv0 = *(const float4*)(xp + k0);
        float4 xv1 = *(const float4*)(xp + k0 + 4);
        const float* __restrict__ wp = W2 + (long long)k0 * OUTC + oq;
        float4 w0 = *(const float4*)(wp + 0 * OUTC);
        float4 w1 = *(const float4*)(wp + 1 * OUTC);
        float4 w2 = *(const float4*)(wp + 2 * OUTC);
        float4 w3 = *(const float4*)(wp + 3 * OUTC);
        float4 w4 = *(const float4*)(wp + 4 * OUTC);
        float4 w5 = *(const float4*)(wp + 5 * OUTC);
        float4 w6 = *(const float4*)(wp + 6 * OUTC);
        float4 w7 = *(const float4*)(wp + 7 * OUTC);
        a0 = fmaf(xv0.x, w0.x, a0); a1 = fmaf(xv0.x, w0.y, a1);
        a2 = fmaf(xv0.x, w0.z, a2); a3 = fmaf(xv0.x, w0.w, a3);
        a0 = fmaf(xv0.y, w1.x, a0); a1 = fmaf(xv0.y, w1.y, a1);
        a2 = fmaf(xv0.y, w1.z, a2); a3 = fmaf(xv0.y, w1.w, a3);
        a0 = fmaf(xv0.z, w2.x, a0); a1 = fmaf(xv0.z, w2.y, a1);
        a2 = fmaf(xv0.z, w2.z, a2); a3 = fmaf(xv0.z, w2.w, a3);
        a0 = fmaf(xv0.w, w3.x, a0); a1 = fmaf(xv0.w, w3.y, a1);
        a2 = fmaf(xv0.w, w3.z, a2); a3 = fmaf(xv0.w, w3.w, a3);
        a0 = fmaf(xv1.x, w4.x, a0); a1 = fmaf(xv1.x, w4.y, a1);
        a2 = fmaf(xv1.x, w4.z, a2); a3 = fmaf(xv1.x, w4.w, a3);
        a0 = fmaf(xv1.y, w5.x, a0); a1 = fmaf(xv1.y, w5.y, a1);
        a2 = fmaf(xv1.y, w5.z, a2); a3 = fmaf(xv1.y, w5.w, a3);
        a0 = fmaf(xv1.z, w6.x, a0); a1 = fmaf(xv1.z, w6.y, a1);
        a2 = fmaf(xv1.z, w6.z, a2); a3 = fmaf(xv1.z, w6.w, a3);
        a0 = fmaf(xv1.w, w7.x, a0); a1 = fmaf(xv1.w, w7.y, a1);
        a2 = fmaf(xv1.w, w7.z, a2); a3 = fmaf(xv1.w, w7.w, a3);
    }
    float di = dinv[node];
    *(float4*)(h2s + node * OUTC + oq) = make_float4(a0 * di, a1 * di, a2 * di, a3 * di);
}

// ---------------- layer-2 pull aggregation + fused finalize ----------------
__global__ __launch_bounds__(256) void k_agg2csr(const int* __restrict__ ptr,
                                                 const int* __restrict__ cnt,
                                                 const int* __restrict__ csr_src,
                                                 const float* __restrict__ dinv,
                                                 const float* __restrict__ h2s,
                                                 const float* __restrict__ b2,
                                                 float* __restrict__ out, int n) {
    long long g = (long long)blockIdx.x * blockDim.x + threadIdx.x;
    int node = (int)(g >> 4);
    int ch = (int)(g & 15);
    if (node >= n) return;
    float acc = h2s[(long long)node * OUTC + ch];
    int st = ptr[node], deg = cnt[node];
    int j = 0;
    for (; j + 3 < deg; j += 4) {
        int s0 = csr_src[st + j], s1 = csr_src[st + j + 1];
        int s2 = csr_src[st + j + 2], s3 = csr_src[st + j + 3];
        float a0 = h2s[(long long)s0 * OUTC + ch];
        float a1 = h2s[(long long)s1 * OUTC + ch];
        float a2 = h2s[(long long)s2 * OUTC + ch];
        float a3 = h2s[(long long)s3 * OUTC + ch];
        acc += (a0 + a1) + (a2 + a3);
    }
    for (; j < deg; ++j)
        acc += h2s[(long long)csr_src[st + j] * OUTC + ch];
    out[(long long)node * OUTC + ch] = acc * dinv[node] + b2[ch];
}

extern "C" void kernel_launch(void* const* d_in, const int* in_sizes, int n_in,
                              void* d_out, int out_size, void* d_ws, size_t ws_size,
                              hipStream_t stream) {
    const float* x  = (const float*)d_in[0];
    const int*   ei = (const int*)d_in[1];
    const float* W1 = (const float*)d_in[2];
    const float* b1 = (const float*)d_in[3];
    const float* W2 = (const float*)d_in[4];
    const float* b2 = (const float*)d_in[5];
    const int n = in_sizes[0] / IN_C;            // 100000
    const long long E = in_sizes[1] / 2;         // 3200000
    float* out = (float*)d_out;

    const int nbkt = (n + NPB - 1) / NPB;        // 782

    char* ws = (char*)d_ws;
    size_t off = 0;
    auto alloc = [&](size_t bytes) { void* p = ws + off; off += (bytes + 255) & ~(size_t)255; return p; };
    int*      flag     = (int*)alloc(256);
    int*      bkt_cnt  = (int*)alloc((size_t)MAXBKT * 4);
    int*      bkt_base = (int*)alloc((size_t)MAXBKT * 4);
    int*      bkt_cur  = (int*)alloc((size_t)MAXBKT * 4);
    float*    dinv     = (float*)alloc((size_t)n * 4);
    int*      cnt      = (int*)alloc((size_t)n * 4);
    int*      ptr      = (int*)alloc((size_t)n * 4);
    unsigned* packed   = (unsigned*)alloc((size_t)E * 4);
    int*      csr_src  = (int*)alloc((size_t)E * 4);
    float*    h1s      = (float*)alloc((size_t)n * HIDC * 4);
    float*    h1r      = (float*)alloc((size_t)n * HIDC * 4);
    float*    h2s      = h1s;  // h1s dead after k_agg1csr; reuse

    hipMemsetAsync(bkt_cnt, 0, (size_t)nbkt * 4, stream);

    k_detect<<<1, 256, 0, stream>>>(ei, flag);
    k_bin_count<<<1024, 256, 0, stream>>>(ei, E, flag, bkt_cnt, nbkt);
    k_bscan<<<1, 512, 0, stream>>>(bkt_cnt, bkt_base, bkt_cur, nbkt);
    k_bin_scatter<<<1024, 256, 0, stream>>>(ei, E, flag, bkt_cur, packed, nbkt);
    k_bucket_csr<<<nbkt, 256, 0, stream>>>(packed, bkt_base, bkt_cnt, csr_src, ptr, cnt, dinv, n);

    k_gemm1<<<(n + G1_NODES - 1) / G1_NODES, 256, 0, stream>>>(x, W1, dinv, h1s, n);
    k_agg1csr<<<(int)(((long long)n * HIDC + 255) / 256), 256, 0, stream>>>(
        ptr, cnt, csr_src, dinv, h1s, b1, h1r, n);
    k_gemm2<<<(n + 63) / 64, 256, 0, stream>>>(h1r, W2, dinv, h2s, n);
    k_agg2csr<<<(int)(((long long)n * OUTC + 255) / 256), 256, 0, stream>>>(
        ptr, cnt, csr_src, dinv, h2s, b2, out, n);
}

// Round 11
// 238.724 us; speedup vs baseline: 1.1964x; 1.1964x over previous
//
#include <hip/hip_runtime.h>

#define IN_C 256
#define HIDC 32
#define OUTC 16
#define NPB  128          // nodes per bucket (d_local = 7 bits)
#define MAXBKT 800        // >= ceil(100000/128) = 782

// ---------------- edge index loader (handles int32 or int64 storage) -------
__device__ __forceinline__ int edge_at(const int* __restrict__ ei, long long idx, int is64) {
    return is64 ? ei[idx << 1] : ei[idx];
}

// Detect int64 vs int32 storage: sample odd 32-bit words; all-zero => int64.
__global__ void k_detect(const int* __restrict__ ei, int* __restrict__ flag) {
    __shared__ int nz;
    if (threadIdx.x == 0) nz = 0;
    __syncthreads();
    if (ei[2 * threadIdx.x + 1] != 0) atomicOr(&nz, 1);
    __syncthreads();
    if (threadIdx.x == 0) *flag = (nz == 0) ? 1 : 0;
}

// ---------------- bucket binning -------------------------------------------
// 256 blocks x 1024 threads (round-10 lesson: MORE BLOCKS shrank per-
// (block,bucket) write runs 64B->16B -> 8x write amp + L2 thrash, SLOWER.
// Bigger blocks keep 64B runs while quadrupling waves/CU: 4 -> 16, 50% cap).
__global__ __launch_bounds__(1024) void k_bin_count(const int* __restrict__ ei, long long E,
                                                    const int* __restrict__ flag,
                                                    int* __restrict__ bkt_cnt, int nbkt) {
    __shared__ int hist[MAXBKT];
    int is64 = *flag;
    for (int i = threadIdx.x; i < nbkt; i += 1024) hist[i] = 0;
    __syncthreads();
    long long chunk = (E + gridDim.x - 1) / gridDim.x;
    long long lo = (long long)blockIdx.x * chunk;
    long long hi = lo + chunk; if (hi > E) hi = E;
    for (long long i = lo + threadIdx.x; i < hi; i += 1024)
        atomicAdd(&hist[edge_at(ei, E + i, is64) >> 7], 1);
    __syncthreads();
    for (int b = threadIdx.x; b < nbkt; b += 1024)
        if (hist[b]) atomicAdd(&bkt_cnt[b], hist[b]);
}

__global__ __launch_bounds__(512) void k_bscan(const int* __restrict__ bkt_cnt,
                                               int* __restrict__ bkt_base,
                                               int* __restrict__ bkt_cur, int nbkt) {
    __shared__ int sm[512];
    int t = threadIdx.x;
    int e0 = (2 * t < nbkt) ? bkt_cnt[2 * t] : 0;
    int e1 = (2 * t + 1 < nbkt) ? bkt_cnt[2 * t + 1] : 0;
    int pv = e0 + e1;
    sm[t] = pv;
    __syncthreads();
    for (int o = 1; o < 512; o <<= 1) {
        int x = (t >= o) ? sm[t - o] : 0;
        __syncthreads();
        sm[t] += x;
        __syncthreads();
    }
    int base = sm[t] - pv;  // exclusive over pairs
    if (2 * t < nbkt)     { bkt_base[2 * t] = base;          bkt_cur[2 * t] = base; }
    if (2 * t + 1 < nbkt) { bkt_base[2 * t + 1] = base + e0; bkt_cur[2 * t + 1] = base + e0; }
}

__global__ __launch_bounds__(1024) void k_bin_scatter(const int* __restrict__ ei, long long E,
                                                      const int* __restrict__ flag,
                                                      int* __restrict__ bkt_cur,
                                                      unsigned* __restrict__ packed, int nbkt) {
    __shared__ int hist[MAXBKT];
    int is64 = *flag;
    for (int i = threadIdx.x; i < nbkt; i += 1024) hist[i] = 0;
    __syncthreads();
    long long chunk = (E + gridDim.x - 1) / gridDim.x;
    long long lo = (long long)blockIdx.x * chunk;
    long long hi = lo + chunk; if (hi > E) hi = E;
    for (long long i = lo + threadIdx.x; i < hi; i += 1024)
        atomicAdd(&hist[edge_at(ei, E + i, is64) >> 7], 1);
    __syncthreads();
    for (int b = threadIdx.x; b < nbkt; b += 1024) {
        int c = hist[b];
        hist[b] = c ? atomicAdd(&bkt_cur[b], c) : 0;   // hist now = running cursor
    }
    __syncthreads();
    for (long long i = lo + threadIdx.x; i < hi; i += 1024) {
        int s = edge_at(ei, i, is64);
        int d = edge_at(ei, E + i, is64);
        int slot = atomicAdd(&hist[d >> 7], 1);
        packed[slot] = (unsigned)s | ((unsigned)(d & (NPB - 1)) << 20);
    }
}

// ---------------- per-bucket counting sort -> node-level CSR ---------------
__global__ __launch_bounds__(256) void k_bucket_csr(const unsigned* __restrict__ packed,
                                                    const int* __restrict__ bkt_base,
                                                    const int* __restrict__ bkt_cnt,
                                                    int* __restrict__ csr_src,
                                                    int* __restrict__ ptr,
                                                    int* __restrict__ cnt,
                                                    float* __restrict__ dinv, int n) {
    __shared__ int hist[NPB];
    __shared__ int off[NPB];
    if (threadIdx.x < NPB) hist[threadIdx.x] = 0;
    __syncthreads();
    int base = bkt_base[blockIdx.x], m = bkt_cnt[blockIdx.x];
    for (int i = threadIdx.x; i < m; i += 256)
        atomicAdd(&hist[packed[base + i] >> 20], 1);
    __syncthreads();
    if (threadIdx.x < NPB) off[threadIdx.x] = hist[threadIdx.x];
    __syncthreads();
    for (int o = 1; o < NPB; o <<= 1) {
        int v = 0;
        if (threadIdx.x < NPB && threadIdx.x >= o) v = off[threadIdx.x - o];
        __syncthreads();
        if (threadIdx.x < NPB) off[threadIdx.x] += v;
        __syncthreads();
    }
    int node = blockIdx.x * NPB + threadIdx.x;
    if (threadIdx.x < NPB) {
        int exc = off[threadIdx.x] - hist[threadIdx.x];
        if (node < n) {
            ptr[node]  = base + exc;
            cnt[node]  = hist[threadIdx.x];
            dinv[node] = rsqrtf((float)hist[threadIdx.x] + 1.0f);
        }
        hist[threadIdx.x] = exc;                  // reuse as cursor
    }
    __syncthreads();
    for (int i = threadIdx.x; i < m; i += 256) {
        unsigned w = packed[base + i];
        int r = atomicAdd(&hist[w >> 20], 1);
        csr_src[base + r] = (int)(w & 0xFFFFF);   // write inside bucket window
    }
}

// ---------------- gemm1: h1s = (x @ W1) * dinv  [n,256]x[256,32] ------------
// lane = node (64/block); wave q fully owns o-octet [8q,8q+8) -> acc is 8
// STATIC scalars (round-8 lesson: runtime-indexed acc -> scratch). x and W
// both staged in LDS; W read as wave-uniform float4 broadcasts.
#define G1_NODES 64
__global__ __launch_bounds__(256) void k_gemm1(const float* __restrict__ x,
                                               const float* __restrict__ W1,
                                               const float* __restrict__ dinv,
                                               float* __restrict__ h1s, int n) {
    __shared__ float xs[G1_NODES][33];   // 8.4 KB; bank(lane,k) = (lane+k)%32
    __shared__ float wl[32][36];         // 4.6 KB; rows 16B-aligned (36%4==0)
    const int t = threadIdx.x;
    const int lane = t & 63;
    const int oq0 = (t >> 6) * 8;        // wave's o-octet base
    const long long nb0 = (long long)blockIdx.x * G1_NODES;
    const long long node = nb0 + lane;
    const bool valid = node < n;

    float a0 = 0.f, a1 = 0.f, a2 = 0.f, a3 = 0.f;
    float a4 = 0.f, a5 = 0.f, a6 = 0.f, a7 = 0.f;

    for (int c = 0; c < IN_C / 32; ++c) {          // 8 chunks of 32 k
        const int k0 = c * 32;
#pragma unroll
        for (int j = 0; j < 2; ++j) {
            int f = j * 256 + t;
            int row = f >> 3, c4 = f & 7;
            long long nd = nb0 + row;
            float4 v = make_float4(0.f, 0.f, 0.f, 0.f);
            if (nd < n) v = *(const float4*)(x + nd * IN_C + k0 + c4 * 4);
            xs[row][c4 * 4 + 0] = v.x; xs[row][c4 * 4 + 1] = v.y;
            xs[row][c4 * 4 + 2] = v.z; xs[row][c4 * 4 + 3] = v.w;
        }
        {
            int kk = t >> 3, o4 = (t & 7) * 4;
            float4 w = *(const float4*)(W1 + (long long)(k0 + kk) * HIDC + o4);
            wl[kk][o4 + 0] = w.x; wl[kk][o4 + 1] = w.y;
            wl[kk][o4 + 2] = w.z; wl[kk][o4 + 3] = w.w;
        }
        __syncthreads();
#pragma unroll
        for (int g = 0; g < 8; ++g) {              // 4 k per group
            const int kb = g * 4;
            float x0 = xs[lane][kb + 0];
            float x1 = xs[lane][kb + 1];
            float x2 = xs[lane][kb + 2];
            float x3 = xs[lane][kb + 3];
            float4 wa0 = *(const float4*)&wl[kb + 0][oq0];
            float4 wb0 = *(const float4*)&wl[kb + 0][oq0 + 4];
            float4 wa1 = *(const float4*)&wl[kb + 1][oq0];
            float4 wb1 = *(const float4*)&wl[kb + 1][oq0 + 4];
            float4 wa2 = *(const float4*)&wl[kb + 2][oq0];
            float4 wb2 = *(const float4*)&wl[kb + 2][oq0 + 4];
            float4 wa3 = *(const float4*)&wl[kb + 3][oq0];
            float4 wb3 = *(const float4*)&wl[kb + 3][oq0 + 4];
            a0 = fmaf(x0, wa0.x, a0); a1 = fmaf(x0, wa0.y, a1);
            a2 = fmaf(x0, wa0.z, a2); a3 = fmaf(x0, wa0.w, a3);
            a4 = fmaf(x0, wb0.x, a4); a5 = fmaf(x0, wb0.y, a5);
            a6 = fmaf(x0, wb0.z, a6); a7 = fmaf(x0, wb0.w, a7);
            a0 = fmaf(x1, wa1.x, a0); a1 = fmaf(x1, wa1.y, a1);
            a2 = fmaf(x1, wa1.z, a2); a3 = fmaf(x1, wa1.w, a3);
            a4 = fmaf(x1, wb1.x, a4); a5 = fmaf(x1, wb1.y, a5);
            a6 = fmaf(x1, wb1.z, a6); a7 = fmaf(x1, wb1.w, a7);
            a0 = fmaf(x2, wa2.x, a0); a1 = fmaf(x2, wa2.y, a1);
            a2 = fmaf(x2, wa2.z, a2); a3 = fmaf(x2, wa2.w, a3);
            a4 = fmaf(x2, wb2.x, a4); a5 = fmaf(x2, wb2.y, a5);
            a6 = fmaf(x2, wb2.z, a6); a7 = fmaf(x2, wb2.w, a7);
            a0 = fmaf(x3, wa3.x, a0); a1 = fmaf(x3, wa3.y, a1);
            a2 = fmaf(x3, wa3.z, a2); a3 = fmaf(x3, wa3.w, a3);
            a4 = fmaf(x3, wb3.x, a4); a5 = fmaf(x3, wb3.y, a5);
            a6 = fmaf(x3, wb3.z, a6); a7 = fmaf(x3, wb3.w, a7);
        }
        __syncthreads();
    }
    if (valid) {
        float di = dinv[node];
        *(float4*)(h1s + node * HIDC + oq0) =
            make_float4(a0 * di, a1 * di, a2 * di, a3 * di);
        *(float4*)(h1s + node * HIDC + oq0 + 4) =
            make_float4(a4 * di, a5 * di, a6 * di, a7 * di);
    }
}

// ---------------- layer-1 pull aggregation + fused finalize ----------------
__global__ __launch_bounds__(256) void k_agg1csr(const int* __restrict__ ptr,
                                                 const int* __restrict__ cnt,
                                                 const int* __restrict__ csr_src,
                                                 const float* __restrict__ dinv,
                                                 const float* __restrict__ h1s,
                                                 const float* __restrict__ b1,
                                                 float* __restrict__ h1r, int n) {
    long long g = (long long)blockIdx.x * blockDim.x + threadIdx.x;
    int node = (int)(g >> 5);
    int ch = (int)(g & 31);
    if (node >= n) return;
    float acc = h1s[(long long)node * HIDC + ch];   // self-loop term (x dinv already)
    int st = ptr[node], deg = cnt[node];
    int j = 0;
    for (; j + 3 < deg; j += 4) {
        int s0 = csr_src[st + j], s1 = csr_src[st + j + 1];
        int s2 = csr_src[st + j + 2], s3 = csr_src[st + j + 3];
        float a0 = h1s[(long long)s0 * HIDC + ch];
        float a1 = h1s[(long long)s1 * HIDC + ch];
        float a2 = h1s[(long long)s2 * HIDC + ch];
        float a3 = h1s[(long long)s3 * HIDC + ch];
        acc += (a0 + a1) + (a2 + a3);
    }
    for (; j < deg; ++j)
        acc += h1s[(long long)csr_src[st + j] * HIDC + ch];
    float v = acc * dinv[node] + b1[ch];
    h1r[(long long)node * HIDC + ch] = v > 0.f ? v : 0.f;
}

// ---------------- gemm2: h2s = (h1r @ W2) * dinv  [n,32]x[32,16] ------------
__global__ __launch_bounds__(256) void k_gemm2(const float* __restrict__ h1,
                                               const float* __restrict__ W2,
                                               const float* __restrict__ dinv,
                                               float* __restrict__ h2s, int n) {
    const int t = threadIdx.x;
    const int oq = (t & 3) * 4;
    const long long node = (long long)blockIdx.x * 64 + (t >> 2);
    if (node >= n) return;
    const float* __restrict__ xp = h1 + node * HIDC;
    float a0 = 0.f, a1 = 0.f, a2 = 0.f, a3 = 0.f;
#pragma unroll
    for (int k0 = 0; k0 < HIDC; k0 += 8) {
        float4 xv0 = *(const float4*)(xp + k0);
        float4 xv1 = *(const float4*)(xp + k0 + 4);
        const float* __restrict__ wp = W2 + (long long)k0 * OUTC + oq;
        float4 w0 = *(const float4*)(wp + 0 * OUTC);
        float4 w1 = *(const float4*)(wp + 1 * OUTC);
        float4 w2 = *(const float4*)(wp + 2 * OUTC);
        float4 w3 = *(const float4*)(wp + 3 * OUTC);
        float4 w4 = *(const float4*)(wp + 4 * OUTC);
        float4 w5 = *(const float4*)(wp + 5 * OUTC);
        float4 w6 = *(const float4*)(wp + 6 * OUTC);
        float4 w7 = *(const float4*)(wp + 7 * OUTC);
        a0 = fmaf(xv0.x, w0.x, a0); a1 = fmaf(xv0.x, w0.y, a1);
        a2 = fmaf(xv0.x, w0.z, a2); a3 = fmaf(xv0.x, w0.w, a3);
        a0 = fmaf(xv0.y, w1.x, a0); a1 = fmaf(xv0.y, w1.y, a1);
        a2 = fmaf(xv0.y, w1.z, a2); a3 = fmaf(xv0.y, w1.w, a3);
        a0 = fmaf(xv0.z, w2.x, a0); a1 = fmaf(xv0.z, w2.y, a1);
        a2 = fmaf(xv0.z, w2.z, a2); a3 = fmaf(xv0.z, w2.w, a3);
        a0 = fmaf(xv0.w, w3.x, a0); a1 = fmaf(xv0.w, w3.y, a1);
        a2 = fmaf(xv0.w, w3.z, a2); a3 = fmaf(xv0.w, w3.w, a3);
        a0 = fmaf(xv1.x, w4.x, a0); a1 = fmaf(xv1.x, w4.y, a1);
        a2 = fmaf(xv1.x, w4.z, a2); a3 = fmaf(xv1.x, w4.w, a3);
        a0 = fmaf(xv1.y, w5.x, a0); a1 = fmaf(xv1.y, w5.y, a1);
        a2 = fmaf(xv1.y, w5.z, a2); a3 = fmaf(xv1.y, w5.w, a3);
        a0 = fmaf(xv1.z, w6.x, a0); a1 = fmaf(xv1.z, w6.y, a1);
        a2 = fmaf(xv1.z, w6.z, a2); a3 = fmaf(xv1.z, w6.w, a3);
        a0 = fmaf(xv1.w, w7.x, a0); a1 = fmaf(xv1.w, w7.y, a1);
        a2 = fmaf(xv1.w, w7.z, a2); a3 = fmaf(xv1.w, w7.w, a3);
    }
    float di = dinv[node];
    *(float4*)(h2s + node * OUTC + oq) = make_float4(a0 * di, a1 * di, a2 * di, a3 * di);
}

// ---------------- layer-2 pull aggregation + fused finalize ----------------
__global__ __launch_bounds__(256) void k_agg2csr(const int* __restrict__ ptr,
                                                 const int* __restrict__ cnt,
                                                 const int* __restrict__ csr_src,
                                                 const float* __restrict__ dinv,
                                                 const float* __restrict__ h2s,
                                                 const float* __restrict__ b2,
                                                 float* __restrict__ out, int n) {
    long long g = (long long)blockIdx.x * blockDim.x + threadIdx.x;
    int node = (int)(g >> 4);
    int ch = (int)(g & 15);
    if (node >= n) return;
    float acc = h2s[(long long)node * OUTC + ch];
    int st = ptr[node], deg = cnt[node];
    int j = 0;
    for (; j + 3 < deg; j += 4) {
        int s0 = csr_src[st + j], s1 = csr_src[st + j + 1];
        int s2 = csr_src[st + j + 2], s3 = csr_src[st + j + 3];
        float a0 = h2s[(long long)s0 * OUTC + ch];
        float a1 = h2s[(long long)s1 * OUTC + ch];
        float a2 = h2s[(long long)s2 * OUTC + ch];
        float a3 = h2s[(long long)s3 * OUTC + ch];
        acc += (a0 + a1) + (a2 + a3);
    }
    for (; j < deg; ++j)
        acc += h2s[(long long)csr_src[st + j] * OUTC + ch];
    out[(long long)node * OUTC + ch] = acc * dinv[node] + b2[ch];
}

extern "C" void kernel_launch(void* const* d_in, const int* in_sizes, int n_in,
                              void* d_out, int out_size, void* d_ws, size_t ws_size,
                              hipStream_t stream) {
    const float* x  = (const float*)d_in[0];
    const int*   ei = (const int*)d_in[1];
    const float* W1 = (const float*)d_in[2];
    const float* b1 = (const float*)d_in[3];
    const float* W2 = (const float*)d_in[4];
    const float* b2 = (const float*)d_in[5];
    const int n = in_sizes[0] / IN_C;            // 100000
    const long long E = in_sizes[1] / 2;         // 3200000
    float* out = (float*)d_out;

    const int nbkt = (n + NPB - 1) / NPB;        // 782

    char* ws = (char*)d_ws;
    size_t off = 0;
    auto alloc = [&](size_t bytes) { void* p = ws + off; off += (bytes + 255) & ~(size_t)255; return p; };
    int*      flag     = (int*)alloc(256);
    int*      bkt_cnt  = (int*)alloc((size_t)MAXBKT * 4);
    int*      bkt_base = (int*)alloc((size_t)MAXBKT * 4);
    int*      bkt_cur  = (int*)alloc((size_t)MAXBKT * 4);
    float*    dinv     = (float*)alloc((size_t)n * 4);
    int*      cnt      = (int*)alloc((size_t)n * 4);
    int*      ptr      = (int*)alloc((size_t)n * 4);
    unsigned* packed   = (unsigned*)alloc((size_t)E * 4);
    int*      csr_src  = (int*)alloc((size_t)E * 4);
    float*    h1s      = (float*)alloc((size_t)n * HIDC * 4);
    float*    h1r      = (float*)alloc((size_t)n * HIDC * 4);
    float*    h2s      = h1s;  // h1s dead after k_agg1csr; reuse

    hipMemsetAsync(bkt_cnt, 0, (size_t)nbkt * 4, stream);

    k_detect<<<1, 256, 0, stream>>>(ei, flag);
    k_bin_count<<<256, 1024, 0, stream>>>(ei, E, flag, bkt_cnt, nbkt);
    k_bscan<<<1, 512, 0, stream>>>(bkt_cnt, bkt_base, bkt_cur, nbkt);
    k_bin_scatter<<<256, 1024, 0, stream>>>(ei, E, flag, bkt_cur, packed, nbkt);
    k_bucket_csr<<<nbkt, 256, 0, stream>>>(packed, bkt_base, bkt_cnt, csr_src, ptr, cnt, dinv, n);

    k_gemm1<<<(n + G1_NODES - 1) / G1_NODES, 256, 0, stream>>>(x, W1, dinv, h1s, n);
    k_agg1csr<<<(int)(((long long)n * HIDC + 255) / 256), 256, 0, stream>>>(
        ptr, cnt, csr_src, dinv, h1s, b1, h1r, n);
    k_gemm2<<<(n + 63) / 64, 256, 0, stream>>>(h1r, W2, dinv, h2s, n);
    k_agg2csr<<<(int)(((long long)n * OUTC + 255) / 256), 256, 0, stream>>>(
        ptr, cnt, csr_src, dinv, h2s, b2, out, n);
}

// Round 12
// 209.995 us; speedup vs baseline: 1.3601x; 1.1368x over previous
//
#include <hip/hip_runtime.h>

#define IN_C 256
#define HIDC 32
#define OUTC 16
#define NPB  128          // nodes per bucket (d_local = 7 bits)
#define MAXBKT 800        // >= ceil(100000/128) = 782

// ---------------- bf16 helpers ---------------------------------------------
__device__ __forceinline__ unsigned bf16pair(float a, float b) {   // RNE pack
    unsigned ua = __float_as_uint(a); ua += 0x7FFF + ((ua >> 16) & 1);
    unsigned ub = __float_as_uint(b); ub += 0x7FFF + ((ub >> 16) & 1);
    return (ua >> 16) | (ub & 0xFFFF0000u);
}
__device__ __forceinline__ float bf16lo(unsigned u) { return __uint_as_float(u << 16); }
__device__ __forceinline__ float bf16hi(unsigned u) { return __uint_as_float(u & 0xFFFF0000u); }

// ---------------- edge index loader (handles int32 or int64 storage) -------
__device__ __forceinline__ int edge_at(const int* __restrict__ ei, long long idx, int is64) {
    return is64 ? ei[idx << 1] : ei[idx];
}

__global__ void k_detect(const int* __restrict__ ei, int* __restrict__ flag) {
    __shared__ int nz;
    if (threadIdx.x == 0) nz = 0;
    __syncthreads();
    if (ei[2 * threadIdx.x + 1] != 0) atomicOr(&nz, 1);
    __syncthreads();
    if (threadIdx.x == 0) *flag = (nz == 0) ? 1 : 0;
}

// ---------------- bucket binning (256 blocks x 1024 thr — round-10/11) -----
__global__ __launch_bounds__(1024) void k_bin_count(const int* __restrict__ ei, long long E,
                                                    const int* __restrict__ flag,
                                                    int* __restrict__ bkt_cnt, int nbkt) {
    __shared__ int hist[MAXBKT];
    int is64 = *flag;
    for (int i = threadIdx.x; i < nbkt; i += 1024) hist[i] = 0;
    __syncthreads();
    long long chunk = (E + gridDim.x - 1) / gridDim.x;
    long long lo = (long long)blockIdx.x * chunk;
    long long hi = lo + chunk; if (hi > E) hi = E;
    for (long long i = lo + threadIdx.x; i < hi; i += 1024)
        atomicAdd(&hist[edge_at(ei, E + i, is64) >> 7], 1);
    __syncthreads();
    for (int b = threadIdx.x; b < nbkt; b += 1024)
        if (hist[b]) atomicAdd(&bkt_cnt[b], hist[b]);
}

__global__ __launch_bounds__(512) void k_bscan(const int* __restrict__ bkt_cnt,
                                               int* __restrict__ bkt_base,
                                               int* __restrict__ bkt_cur, int nbkt) {
    __shared__ int sm[512];
    int t = threadIdx.x;
    int e0 = (2 * t < nbkt) ? bkt_cnt[2 * t] : 0;
    int e1 = (2 * t + 1 < nbkt) ? bkt_cnt[2 * t + 1] : 0;
    int pv = e0 + e1;
    sm[t] = pv;
    __syncthreads();
    for (int o = 1; o < 512; o <<= 1) {
        int x = (t >= o) ? sm[t - o] : 0;
        __syncthreads();
        sm[t] += x;
        __syncthreads();
    }
    int base = sm[t] - pv;
    if (2 * t < nbkt)     { bkt_base[2 * t] = base;          bkt_cur[2 * t] = base; }
    if (2 * t + 1 < nbkt) { bkt_base[2 * t + 1] = base + e0; bkt_cur[2 * t + 1] = base + e0; }
}

__global__ __launch_bounds__(1024) void k_bin_scatter(const int* __restrict__ ei, long long E,
                                                      const int* __restrict__ flag,
                                                      int* __restrict__ bkt_cur,
                                                      unsigned* __restrict__ packed, int nbkt) {
    __shared__ int hist[MAXBKT];
    int is64 = *flag;
    for (int i = threadIdx.x; i < nbkt; i += 1024) hist[i] = 0;
    __syncthreads();
    long long chunk = (E + gridDim.x - 1) / gridDim.x;
    long long lo = (long long)blockIdx.x * chunk;
    long long hi = lo + chunk; if (hi > E) hi = E;
    for (long long i = lo + threadIdx.x; i < hi; i += 1024)
        atomicAdd(&hist[edge_at(ei, E + i, is64) >> 7], 1);
    __syncthreads();
    for (int b = threadIdx.x; b < nbkt; b += 1024) {
        int c = hist[b];
        hist[b] = c ? atomicAdd(&bkt_cur[b], c) : 0;
    }
    __syncthreads();
    for (long long i = lo + threadIdx.x; i < hi; i += 1024) {
        int s = edge_at(ei, i, is64);
        int d = edge_at(ei, E + i, is64);
        int slot = atomicAdd(&hist[d >> 7], 1);
        packed[slot] = (unsigned)s | ((unsigned)(d & (NPB - 1)) << 20);
    }
}

// ---------------- per-bucket counting sort -> node-level CSR ---------------
__global__ __launch_bounds__(256) void k_bucket_csr(const unsigned* __restrict__ packed,
                                                    const int* __restrict__ bkt_base,
                                                    const int* __restrict__ bkt_cnt,
                                                    int* __restrict__ csr_src,
                                                    int* __restrict__ ptr,
                                                    int* __restrict__ cnt,
                                                    float* __restrict__ dinv, int n) {
    __shared__ int hist[NPB];
    __shared__ int off[NPB];
    if (threadIdx.x < NPB) hist[threadIdx.x] = 0;
    __syncthreads();
    int base = bkt_base[blockIdx.x], m = bkt_cnt[blockIdx.x];
    for (int i = threadIdx.x; i < m; i += 256)
        atomicAdd(&hist[packed[base + i] >> 20], 1);
    __syncthreads();
    if (threadIdx.x < NPB) off[threadIdx.x] = hist[threadIdx.x];
    __syncthreads();
    for (int o = 1; o < NPB; o <<= 1) {
        int v = 0;
        if (threadIdx.x < NPB && threadIdx.x >= o) v = off[threadIdx.x - o];
        __syncthreads();
        if (threadIdx.x < NPB) off[threadIdx.x] += v;
        __syncthreads();
    }
    int node = blockIdx.x * NPB + threadIdx.x;
    if (threadIdx.x < NPB) {
        int exc = off[threadIdx.x] - hist[threadIdx.x];
        if (node < n) {
            ptr[node]  = base + exc;
            cnt[node]  = hist[threadIdx.x];
            dinv[node] = rsqrtf((float)hist[threadIdx.x] + 1.0f);
        }
        hist[threadIdx.x] = exc;
    }
    __syncthreads();
    for (int i = threadIdx.x; i < m; i += 256) {
        unsigned w = packed[base + i];
        int r = atomicAdd(&hist[w >> 20], 1);
        csr_src[base + r] = (int)(w & 0xFFFFF);
    }
}

// ---------------- gemm1: h1b = bf16((x @ W1) * dinv)  [n,256]x[256,32] -----
#define G1_NODES 64
__global__ __launch_bounds__(256) void k_gemm1(const float* __restrict__ x,
                                               const float* __restrict__ W1,
                                               const float* __restrict__ dinv,
                                               unsigned* __restrict__ h1b, int n) {
    __shared__ float xs[G1_NODES][33];
    __shared__ float wl[32][36];
    const int t = threadIdx.x;
    const int lane = t & 63;
    const int oq0 = (t >> 6) * 8;
    const long long nb0 = (long long)blockIdx.x * G1_NODES;
    const long long node = nb0 + lane;
    const bool valid = node < n;

    float a0 = 0.f, a1 = 0.f, a2 = 0.f, a3 = 0.f;
    float a4 = 0.f, a5 = 0.f, a6 = 0.f, a7 = 0.f;

    for (int c = 0; c < IN_C / 32; ++c) {
        const int k0 = c * 32;
#pragma unroll
        for (int j = 0; j < 2; ++j) {
            int f = j * 256 + t;
            int row = f >> 3, c4 = f & 7;
            long long nd = nb0 + row;
            float4 v = make_float4(0.f, 0.f, 0.f, 0.f);
            if (nd < n) v = *(const float4*)(x + nd * IN_C + k0 + c4 * 4);
            xs[row][c4 * 4 + 0] = v.x; xs[row][c4 * 4 + 1] = v.y;
            xs[row][c4 * 4 + 2] = v.z; xs[row][c4 * 4 + 3] = v.w;
        }
        {
            int kk = t >> 3, o4 = (t & 7) * 4;
            float4 w = *(const float4*)(W1 + (long long)(k0 + kk) * HIDC + o4);
            wl[kk][o4 + 0] = w.x; wl[kk][o4 + 1] = w.y;
            wl[kk][o4 + 2] = w.z; wl[kk][o4 + 3] = w.w;
        }
        __syncthreads();
#pragma unroll
        for (int g = 0; g < 8; ++g) {
            const int kb = g * 4;
            float x0 = xs[lane][kb + 0];
            float x1 = xs[lane][kb + 1];
            float x2 = xs[lane][kb + 2];
            float x3 = xs[lane][kb + 3];
            float4 wa0 = *(const float4*)&wl[kb + 0][oq0];
            float4 wb0 = *(const float4*)&wl[kb + 0][oq0 + 4];
            float4 wa1 = *(const float4*)&wl[kb + 1][oq0];
            float4 wb1 = *(const float4*)&wl[kb + 1][oq0 + 4];
            float4 wa2 = *(const float4*)&wl[kb + 2][oq0];
            float4 wb2 = *(const float4*)&wl[kb + 2][oq0 + 4];
            float4 wa3 = *(const float4*)&wl[kb + 3][oq0];
            float4 wb3 = *(const float4*)&wl[kb + 3][oq0 + 4];
            a0 = fmaf(x0, wa0.x, a0); a1 = fmaf(x0, wa0.y, a1);
            a2 = fmaf(x0, wa0.z, a2); a3 = fmaf(x0, wa0.w, a3);
            a4 = fmaf(x0, wb0.x, a4); a5 = fmaf(x0, wb0.y, a5);
            a6 = fmaf(x0, wb0.z, a6); a7 = fmaf(x0, wb0.w, a7);
            a0 = fmaf(x1, wa1.x, a0); a1 = fmaf(x1, wa1.y, a1);
            a2 = fmaf(x1, wa1.z, a2); a3 = fmaf(x1, wa1.w, a3);
            a4 = fmaf(x1, wb1.x, a4); a5 = fmaf(x1, wb1.y, a5);
            a6 = fmaf(x1, wb1.z, a6); a7 = fmaf(x1, wb1.w, a7);
            a0 = fmaf(x2, wa2.x, a0); a1 = fmaf(x2, wa2.y, a1);
            a2 = fmaf(x2, wa2.z, a2); a3 = fmaf(x2, wa2.w, a3);
            a4 = fmaf(x2, wb2.x, a4); a5 = fmaf(x2, wb2.y, a5);
            a6 = fmaf(x2, wb2.z, a6); a7 = fmaf(x2, wb2.w, a7);
            a0 = fmaf(x3, wa3.x, a0); a1 = fmaf(x3, wa3.y, a1);
            a2 = fmaf(x3, wa3.z, a2); a3 = fmaf(x3, wa3.w, a3);
            a4 = fmaf(x3, wb3.x, a4); a5 = fmaf(x3, wb3.y, a5);
            a6 = fmaf(x3, wb3.z, a6); a7 = fmaf(x3, wb3.w, a7);
        }
        __syncthreads();
    }
    if (valid) {
        float di = dinv[node];
        uint4 p;
        p.x = bf16pair(a0 * di, a1 * di);
        p.y = bf16pair(a2 * di, a3 * di);
        p.z = bf16pair(a4 * di, a5 * di);
        p.w = bf16pair(a6 * di, a7 * di);
        *(uint4*)(h1b + node * (HIDC / 2) + oq0 / 2) = p;
    }
}

// ---------------- layer-1 pull aggregation (bf16 gathers) ------------------
// 16 lanes per node, each lane owns a channel PAIR (one dword = bf16x2).
__global__ __launch_bounds__(256) void k_agg1csr(const int* __restrict__ ptr,
                                                 const int* __restrict__ cnt,
                                                 const int* __restrict__ csr_src,
                                                 const float* __restrict__ dinv,
                                                 const unsigned* __restrict__ h1b,
                                                 const float* __restrict__ b1,
                                                 float* __restrict__ h1r, int n) {
    long long g = (long long)blockIdx.x * blockDim.x + threadIdx.x;
    int node = (int)(g >> 4);
    int cp = (int)(g & 15);              // channel pair
    if (node >= n) return;
    unsigned us = h1b[(long long)node * 16 + cp];
    float accL = bf16lo(us), accH = bf16hi(us);   // self term (pre-scaled)
    int st = ptr[node], deg = cnt[node];
    int j = 0;
    for (; j + 3 < deg; j += 4) {
        int s0 = csr_src[st + j], s1 = csr_src[st + j + 1];
        int s2 = csr_src[st + j + 2], s3 = csr_src[st + j + 3];
        unsigned u0 = h1b[(long long)s0 * 16 + cp];
        unsigned u1 = h1b[(long long)s1 * 16 + cp];
        unsigned u2 = h1b[(long long)s2 * 16 + cp];
        unsigned u3 = h1b[(long long)s3 * 16 + cp];
        accL += (bf16lo(u0) + bf16lo(u1)) + (bf16lo(u2) + bf16lo(u3));
        accH += (bf16hi(u0) + bf16hi(u1)) + (bf16hi(u2) + bf16hi(u3));
    }
    for (; j < deg; ++j) {
        unsigned u = h1b[(long long)csr_src[st + j] * 16 + cp];
        accL += bf16lo(u); accH += bf16hi(u);
    }
    float di = dinv[node];
    float vL = accL * di + b1[2 * cp];
    float vH = accH * di + b1[2 * cp + 1];
    *(float2*)(h1r + (long long)node * HIDC + 2 * cp) =
        make_float2(vL > 0.f ? vL : 0.f, vH > 0.f ? vH : 0.f);
}

// ---------------- gemm2: h2b = bf16((h1r @ W2) * dinv) ---------------------
__global__ __launch_bounds__(256) void k_gemm2(const float* __restrict__ h1,
                                               const float* __restrict__ W2,
                                               const float* __restrict__ dinv,
                                               unsigned* __restrict__ h2b, int n) {
    const int t = threadIdx.x;
    const int oq = (t & 3) * 4;
    const long long node = (long long)blockIdx.x * 64 + (t >> 2);
    if (node >= n) return;
    const float* __restrict__ xp = h1 + node * HIDC;
    float a0 = 0.f, a1 = 0.f, a2 = 0.f, a3 = 0.f;
#pragma unroll
    for (int k0 = 0; k0 < HIDC; k0 += 8) {
        float4 xv0 = *(const float4*)(xp + k0);
        float4 xv1 = *(const float4*)(xp + k0 + 4);
        const float* __restrict__ wp = W2 + (long long)k0 * OUTC + oq;
        float4 w0 = *(const float4*)(wp + 0 * OUTC);
        float4 w1 = *(const float4*)(wp + 1 * OUTC);
        float4 w2 = *(const float4*)(wp + 2 * OUTC);
        float4 w3 = *(const float4*)(wp + 3 * OUTC);
        float4 w4 = *(const float4*)(wp + 4 * OUTC);
        float4 w5 = *(const float4*)(wp + 5 * OUTC);
        float4 w6 = *(const float4*)(wp + 6 * OUTC);
        float4 w7 = *(const float4*)(wp + 7 * OUTC);
        a0 = fmaf(xv0.x, w0.x, a0); a1 = fmaf(xv0.x, w0.y, a1);
        a2 = fmaf(xv0.x, w0.z, a2); a3 = fmaf(xv0.x, w0.w, a3);
        a0 = fmaf(xv0.y, w1.x, a0); a1 = fmaf(xv0.y, w1.y, a1);
        a2 = fmaf(xv0.y, w1.z, a2); a3 = fmaf(xv0.y, w1.w, a3);
        a0 = fmaf(xv0.z, w2.x, a0); a1 = fmaf(xv0.z, w2.y, a1);
        a2 = fmaf(xv0.z, w2.z, a2); a3 = fmaf(xv0.z, w2.w, a3);
        a0 = fmaf(xv0.w, w3.x, a0); a1 = fmaf(xv0.w, w3.y, a1);
        a2 = fmaf(xv0.w, w3.z, a2); a3 = fmaf(xv0.w, w3.w, a3);
        a0 = fmaf(xv1.x, w4.x, a0); a1 = fmaf(xv1.x, w4.y, a1);
        a2 = fmaf(xv1.x, w4.z, a2); a3 = fmaf(xv1.x, w4.w, a3);
        a0 = fmaf(xv1.y, w5.x, a0); a1 = fmaf(xv1.y, w5.y, a1);
        a2 = fmaf(xv1.y, w5.z, a2); a3 = fmaf(xv1.y, w5.w, a3);
        a0 = fmaf(xv1.z, w6.x, a0); a1 = fmaf(xv1.z, w6.y, a1);
        a2 = fmaf(xv1.z, w6.z, a2); a3 = fmaf(xv1.z, w6.w, a3);
        a0 = fmaf(xv1.w, w7.x, a0); a1 = fmaf(xv1.w, w7.y, a1);
        a2 = fmaf(xv1.w, w7.z, a2); a3 = fmaf(xv1.w, w7.w, a3);
    }
    float di = dinv[node];
    uint2 p;
    p.x = bf16pair(a0 * di, a1 * di);
    p.y = bf16pair(a2 * di, a3 * di);
    *(uint2*)(h2b + node * (OUTC / 2) + oq / 2) = p;
}

// ---------------- layer-2 pull aggregation (bf16 gathers) -> d_out ---------
// 8 lanes per node, each lane owns a channel pair.
__global__ __launch_bounds__(256) void k_agg2csr(const int* __restrict__ ptr,
                                                 const int* __restrict__ cnt,
                                                 const int* __restrict__ csr_src,
                                                 const float* __restrict__ dinv,
                                                 const unsigned* __restrict__ h2b,
                                                 const float* __restrict__ b2,
                                                 float* __restrict__ out, int n) {
    long long g = (long long)blockIdx.x * blockDim.x + threadIdx.x;
    int node = (int)(g >> 3);
    int cp = (int)(g & 7);
    if (node >= n) return;
    unsigned us = h2b[(long long)node * 8 + cp];
    float accL = bf16lo(us), accH = bf16hi(us);
    int st = ptr[node], deg = cnt[node];
    int j = 0;
    for (; j + 3 < deg; j += 4) {
        int s0 = csr_src[st + j], s1 = csr_src[st + j + 1];
        int s2 = csr_src[st + j + 2], s3 = csr_src[st + j + 3];
        unsigned u0 = h2b[(long long)s0 * 8 + cp];
        unsigned u1 = h2b[(long long)s1 * 8 + cp];
        unsigned u2 = h2b[(long long)s2 * 8 + cp];
        unsigned u3 = h2b[(long long)s3 * 8 + cp];
        accL += (bf16lo(u0) + bf16lo(u1)) + (bf16lo(u2) + bf16lo(u3));
        accH += (bf16hi(u0) + bf16hi(u1)) + (bf16hi(u2) + bf16hi(u3));
    }
    for (; j < deg; ++j) {
        unsigned u = h2b[(long long)csr_src[st + j] * 8 + cp];
        accL += bf16lo(u); accH += bf16hi(u);
    }
    float di = dinv[node];
    *(float2*)(out + (long long)node * OUTC + 2 * cp) =
        make_float2(accL * di + b2[2 * cp], accH * di + b2[2 * cp + 1]);
}

extern "C" void kernel_launch(void* const* d_in, const int* in_sizes, int n_in,
                              void* d_out, int out_size, void* d_ws, size_t ws_size,
                              hipStream_t stream) {
    const float* x  = (const float*)d_in[0];
    const int*   ei = (const int*)d_in[1];
    const float* W1 = (const float*)d_in[2];
    const float* b1 = (const float*)d_in[3];
    const float* W2 = (const float*)d_in[4];
    const float* b2 = (const float*)d_in[5];
    const int n = in_sizes[0] / IN_C;            // 100000
    const long long E = in_sizes[1] / 2;         // 3200000
    float* out = (float*)d_out;

    const int nbkt = (n + NPB - 1) / NPB;        // 782

    char* ws = (char*)d_ws;
    size_t off = 0;
    auto alloc = [&](size_t bytes) { void* p = ws + off; off += (bytes + 255) & ~(size_t)255; return p; };
    int*      flag     = (int*)alloc(256);
    int*      bkt_cnt  = (int*)alloc((size_t)MAXBKT * 4);
    int*      bkt_base = (int*)alloc((size_t)MAXBKT * 4);
    int*      bkt_cur  = (int*)alloc((size_t)MAXBKT * 4);
    float*    dinv     = (float*)alloc((size_t)n * 4);
    int*      cnt      = (int*)alloc((size_t)n * 4);
    int*      ptr      = (int*)alloc((size_t)n * 4);
    unsigned* packed   = (unsigned*)alloc((size_t)E * 4);
    int*      csr_src  = (int*)alloc((size_t)E * 4);
    unsigned* h1b      = (unsigned*)alloc((size_t)n * (HIDC / 2) * 4);  // bf16 [n][32]
    float*    h1r      = (float*)alloc((size_t)n * HIDC * 4);
    unsigned* h2b      = (unsigned*)alloc((size_t)n * (OUTC / 2) * 4);  // bf16 [n][16]

    hipMemsetAsync(bkt_cnt, 0, (size_t)nbkt * 4, stream);

    k_detect<<<1, 256, 0, stream>>>(ei, flag);
    k_bin_count<<<256, 1024, 0, stream>>>(ei, E, flag, bkt_cnt, nbkt);
    k_bscan<<<1, 512, 0, stream>>>(bkt_cnt, bkt_base, bkt_cur, nbkt);
    k_bin_scatter<<<256, 1024, 0, stream>>>(ei, E, flag, bkt_cur, packed, nbkt);
    k_bucket_csr<<<nbkt, 256, 0, stream>>>(packed, bkt_base, bkt_cnt, csr_src, ptr, cnt, dinv, n);

    k_gemm1<<<(n + G1_NODES - 1) / G1_NODES, 256, 0, stream>>>(x, W1, dinv, h1b, n);
    k_agg1csr<<<(int)(((long long)n * 16 + 255) / 256), 256, 0, stream>>>(
        ptr, cnt, csr_src, dinv, h1b, b1, h1r, n);
    k_gemm2<<<(n + 63) / 64, 256, 0, stream>>>(h1r, W2, dinv, h2b, n);
    k_agg2csr<<<(int)(((long long)n * 8 + 255) / 256), 256, 0, stream>>>(
        ptr, cnt, csr_src, dinv, h2b, b2, out, n);
}